// Round 20
// baseline (180.845 us; speedup 1.0000x reference)
//
#include <hip/hip_runtime.h>
#include <math.h>

#define Bz 32
#define Sz 4096
#define Hz 32
#define Gz 2
#define Dz 128
#define HIDz 4096
#define QKVz 4608
#define NCHc 32   // combine chunks per (b,y) = blocks; block span <= 128 rows
#define KTs 16    // split-K factor for both GEMMs

static __device__ __forceinline__ void fma4(float4& a, float s, const float4& v) {
  a.x = fmaf(s, v.x, a.x);
  a.y = fmaf(s, v.y, a.y);
  a.z = fmaf(s, v.z, a.z);
  a.w = fmaf(s, v.w, a.w);
}
static __device__ __forceinline__ float dot4(const float4& a, const float4& b, float acc) {
  return fmaf(a.x, b.x, fmaf(a.y, b.y, fmaf(a.z, b.z, fmaf(a.w, b.w, acc))));
}
// direct HBM->LDS, 16 B per lane (wave-uniform LDS base + lane*16 by construction)
static __device__ __forceinline__ void gload16(const float* src, float* ldst) {
  __builtin_amdgcn_global_load_lds(
      (const __attribute__((address_space(1))) void*)src,
      (__attribute__((address_space(3))) void*)ldst, 16, 0, 0);
}

// ---------------- split-K GEMM partial: part[kt][b][j] = sum_{k in chunk} X[b][k]*W[k][j]
// grid (N/64, KTs), block 256. Thread: 4 j-cols x 2 b-rows (high TLP: ~4.5 blocks/CU).
__global__ __launch_bounds__(256) void gemm_partial(
    const float* __restrict__ X, const float* __restrict__ W,
    float* __restrict__ part, int K, int N, int KH) {
  extern __shared__ float hl[];  // [32][KH+4]
  const int stride = KH + 4;
  const int t = threadIdx.x;
  const int k0 = blockIdx.y * KH;
  const int cols4 = KH >> 2;
  const int total4 = Bz * cols4;
  for (int fi = t; fi < total4; fi += 256) {
    const int row = fi / cols4;
    const int c4 = fi - row * cols4;
    const float4 v = *(const float4*)&X[(size_t)row * K + k0 + c4 * 4];
    *(float4*)&hl[row * stride + c4 * 4] = v;
  }
  __syncthreads();
  const int jl = t & 15;
  const int b0 = (t >> 4) * 2;
  const int j = blockIdx.x * 64 + jl * 4;
  float4 acc[2];
  acc[0] = make_float4(0.f, 0.f, 0.f, 0.f);
  acc[1] = make_float4(0.f, 0.f, 0.f, 0.f);
  float4 wa[4], wb[4];
#define LDW(buf, kk)                                                      \
  { _Pragma("unroll") for (int r = 0; r < 4; ++r)                         \
      buf[r] = *(const float4*)&W[(size_t)(k0 + (kk) + r) * N + j]; }
#define FMAW(buf, kk)                                                     \
  { _Pragma("unroll") for (int bi = 0; bi < 2; ++bi) {                    \
      const float4 hb = *(const float4*)&hl[(b0 + bi) * stride + (kk)];   \
      fma4(acc[bi], hb.x, buf[0]);                                        \
      fma4(acc[bi], hb.y, buf[1]);                                        \
      fma4(acc[bi], hb.z, buf[2]);                                        \
      fma4(acc[bi], hb.w, buf[3]); } }
  LDW(wa, 0);
  for (int kk = 0; kk < KH; kk += 8) {
    LDW(wb, kk + 4);
    FMAW(wa, kk);
    if (kk + 8 < KH) LDW(wa, kk + 8);
    FMAW(wb, kk + 4);
  }
#undef LDW
#undef FMAW
  #pragma unroll
  for (int bi = 0; bi < 2; bi++) {
    *(float4*)&part[((size_t)blockIdx.y * Bz + b0 + bi) * N + j] = acc[bi];
  }
}

// ---------------- reduce QKV partials + bias, RoPE, emit qrot (pre-scaled), krot, vnew
__global__ __launch_bounds__(256) void qkv_finish(
    const float* __restrict__ part, const float* __restrict__ bias,
    const int* __restrict__ positions, int KT,
    float* __restrict__ qrot, float* __restrict__ krot, float* __restrict__ vnew) {
  const int t = threadIdx.x;
  const int b = blockIdx.x;
  const int head = blockIdx.y * 4 + (t >> 6);
  const int tp = t & 63;
  const int j0 = head * Dz + tp * 2;
  float s0 = bias[j0];
  float s1 = bias[j0 + 1];
  for (int kt = 0; kt < KT; kt++) {
    const float2 p = *(const float2*)&part[((size_t)kt * Bz + b) * QKVz + j0];
    s0 += p.x;
    s1 += p.y;
  }
  float o0 = s0, o1 = s1;
  if (head < Hz + Gz && tp < 32) {
    const float invf = exp2f(-(float)tp * (13.287712379549449f / 32.0f));
    const float a = (float)positions[b] * invf;
    float sn, cs;
    sincosf(a, &sn, &cs);
    o0 = s0 * cs - s1 * sn;
    o1 = s1 * cs + s0 * sn;
  }
  if (head < Hz) {
    const float sc = 0.08838834764831845f;
    float2 o = make_float2(o0 * sc, o1 * sc);
    *(float2*)&qrot[((size_t)b * Hz + head) * Dz + tp * 2] = o;
  } else if (head < Hz + Gz) {
    float2 o = make_float2(o0, o1);
    *(float2*)&krot[((size_t)b * Gz + (head - Hz)) * Dz + tp * 2] = o;
  } else {
    float2 o = make_float2(s0, s1);
    *(float2*)&vnew[((size_t)b * Gz + (head - Hz - Gz)) * Dz + tp * 2] = o;
  }
}

// ---------------- flash block (8 heads): y = blockIdx.y in [0,4): heads y*8..y*8+7,
// KV group g = y>>1. Block bx owns span [bx*(pos+1)/32, (bx+1)*(pos+1)/32) (<=128 rows).
// Wave w owns rows [w*8, w*8+8) of each 32-row tile, stages its K rows via global_load_lds
// into a wave-private single buffer (no barriers in loop). QK lane (hq,rq,cq): 2 heads
// x 4 rows, Q in registers; reduce over 8 cq lanes. PV lane = d-pair: V direct from
// global; P via wave LDS. ~84 VGPR; cap 128 (256,2) -> NO spill; 4 blocks/CU.
__global__ __launch_bounds__(256, 2) void attn_unit(
    const float* __restrict__ qrot, const float* __restrict__ kcache,
    const float* __restrict__ vcache, const float* __restrict__ krot,
    const float* __restrict__ vnew, const int* __restrict__ positions,
    float* __restrict__ mbuf, float* __restrict__ lbuf, float* __restrict__ pacc) {
  __shared__ float qs[8 * 132];  // Q staging [h 0..7][c4*4], stride 132
  __shared__ float kbw[4][1024]; // per-wave K buffer (8 rows x 128); aliased as Aw
  __shared__ float plw[4][64];   // per-wave P: [s 0..7][h 0..7]
  __shared__ float scw[4][8];    // per-wave rescale factors
  __shared__ float ml[128];      // m: [w*16+h], l: [64 + w*16+h]
  const int y = blockIdx.y, b = blockIdx.z, bx = blockIdx.x;
  const int g = y >> 1;
  const int pos = positions[b];
  const int lt = pos + 1;
  const int blo = (bx * lt) >> 5;
  const int bhi = ((bx + 1) * lt) >> 5;
  const int nr = bhi - blo;
  const int t = threadIdx.x, w = t >> 6, lane = t & 63;
  const int hq = lane >> 4, rq = (lane >> 3) & 1, cq = lane & 7;
  float* kw = kbw[w];
  float* plv = plw[w];

  // Q tile -> LDS once (pre-scaled). 8 heads x 32 float4 = 256 entries = 1 per thread.
  {
    const int h = t >> 5, c4 = t & 31;
    const float4 q = *(const float4*)&qrot[((size_t)b * Hz + y * 8 + h) * Dz + c4 * 4];
    *(float4*)&qs[h * 132 + c4 * 4] = q;
  }

  const float* krow_new = &krot[((size_t)b * Gz + g) * Dz];
  const float* vrow_new = &vnew[((size_t)b * Gz + g) * Dz];
  const size_t kvb = ((size_t)b * Sz) * (Gz * Dz) + (size_t)g * Dz;

#define STAGE(tile) {                                                              \
    const int sg_ = blo + (tile) * 32 + w * 8 + (lane >> 3);                       \
    const bool fr_ = (sg_ >= bhi) || (sg_ == pos);                                 \
    const float* kp_ = fr_ ? krow_new : &kcache[kvb + (size_t)sg_ * (Gz * Dz)];    \
    gload16(kp_ + (lane & 7) * 4,      &kw[0 * 256 + lane * 4]);                   \
    gload16(kp_ + (lane & 7) * 4 + 32, &kw[1 * 256 + lane * 4]);                   \
    gload16(kp_ + (lane & 7) * 4 + 64, &kw[2 * 256 + lane * 4]);                   \
    gload16(kp_ + (lane & 7) * 4 + 96, &kw[3 * 256 + lane * 4]); }

  float m_run[2], l_run[2];
  float2 A2[8];
  #pragma unroll
  for (int i = 0; i < 2; ++i) { m_run[i] = -1e30f; l_run[i] = 0.f; }
  #pragma unroll
  for (int h = 0; h < 8; ++h) A2[h] = make_float2(0.f, 0.f);

  const int ntw = (nr > w * 8) ? ((nr - w * 8 + 31) >> 5) : 0;  // wave-uniform tiles
  __syncthreads();  // qs visible to all waves

  // Q into registers once per block: qr[i][j] = Q[hq*2+i][(cq + 8j)*4 ..]
  float4 qr[2][4];
  #pragma unroll
  for (int i = 0; i < 2; ++i)
    #pragma unroll
    for (int j = 0; j < 4; ++j)
      qr[i][j] = *(const float4*)&qs[(hq * 2 + i) * 132 + (cq + 8 * j) * 4];

  for (int tile = 0; tile < ntw; ++tile) {
    STAGE(tile);
    // ---- QK: K from wave LDS buffer, Q from registers
    float lp[2][4];
    #pragma unroll
    for (int i = 0; i < 2; ++i)
      #pragma unroll
      for (int s = 0; s < 4; ++s) lp[i][s] = 0.f;
    #pragma unroll
    for (int j = 0; j < 4; ++j) {
      float4 kf[4];
      #pragma unroll
      for (int s = 0; s < 4; ++s)
        kf[s] = *(const float4*)&kw[j * 256 + ((rq * 4 + s) * 8 + cq) * 4];
      #pragma unroll
      for (int i = 0; i < 2; ++i) {
        #pragma unroll
        for (int s = 0; s < 4; ++s) lp[i][s] = dot4(qr[i][j], kf[s], lp[i][s]);
      }
    }
    // reduce over cq lanes
    #pragma unroll
    for (int i = 0; i < 2; ++i)
      #pragma unroll
      for (int s = 0; s < 4; ++s) {
        lp[i][s] += __shfl_xor(lp[i][s], 1);
        lp[i][s] += __shfl_xor(lp[i][s], 2);
        lp[i][s] += __shfl_xor(lp[i][s], 4);
      }
    // mask rows beyond span
    const int rbase = tile * 32 + w * 8 + rq * 4;
    #pragma unroll
    for (int s = 0; s < 4; ++s) {
      if (rbase + s >= nr) {
        lp[0][s] = -1e30f;
        lp[1][s] = -1e30f;
      }
    }
    // ---- online softmax per head
    float sc[2];
    #pragma unroll
    for (int i = 0; i < 2; ++i) {
      float tm = fmaxf(fmaxf(lp[i][0], lp[i][1]), fmaxf(lp[i][2], lp[i][3]));
      tm = fmaxf(tm, __shfl_xor(tm, 8));
      const float mn = fmaxf(m_run[i], tm);
      sc[i] = __expf(m_run[i] - mn);
      m_run[i] = mn;
      float ts = 0.f;
      #pragma unroll
      for (int s = 0; s < 4; ++s) {
        lp[i][s] = __expf(lp[i][s] - mn);
        ts += lp[i][s];
      }
      ts += __shfl_xor(ts, 8);
      l_run[i] = l_run[i] * sc[i] + ts;
    }
    // ---- handoff P and sc (wave-private LDS; same-wave ordering)
    if (cq == 0) {
      if (rq == 0) *(float2*)&scw[w][hq * 2] = make_float2(sc[0], sc[1]);
      #pragma unroll
      for (int s = 0; s < 4; ++s)
        *(float2*)&plv[(rq * 4 + s) * 8 + hq * 2] = make_float2(lp[0][s], lp[1][s]);
    }
    // ---- PV: rescale A2, then accumulate (V direct from global, coalesced)
    {
      const float4 s0 = *(const float4*)&scw[w][0];
      const float4 s1 = *(const float4*)&scw[w][4];
      A2[0].x *= s0.x; A2[0].y *= s0.x;  A2[1].x *= s0.y; A2[1].y *= s0.y;
      A2[2].x *= s0.z; A2[2].y *= s0.z;  A2[3].x *= s0.w; A2[3].y *= s0.w;
      A2[4].x *= s1.x; A2[4].y *= s1.x;  A2[5].x *= s1.y; A2[5].y *= s1.y;
      A2[6].x *= s1.z; A2[6].y *= s1.z;  A2[7].x *= s1.w; A2[7].y *= s1.w;
    }
    #pragma unroll
    for (int s = 0; s < 8; ++s) {
      const int sg = blo + tile * 32 + w * 8 + s;          // wave-uniform
      const float* vp = (sg >= bhi || sg == pos) ? vrow_new
                         : &vcache[kvb + (size_t)sg * (Gz * Dz)];
      const float2 v2 = *(const float2*)&vp[lane * 2];
      const float4 p0 = *(const float4*)&plv[s * 8 + 0];
      const float4 p1 = *(const float4*)&plv[s * 8 + 4];
      A2[0].x = fmaf(p0.x, v2.x, A2[0].x);  A2[0].y = fmaf(p0.x, v2.y, A2[0].y);
      A2[1].x = fmaf(p0.y, v2.x, A2[1].x);  A2[1].y = fmaf(p0.y, v2.y, A2[1].y);
      A2[2].x = fmaf(p0.z, v2.x, A2[2].x);  A2[2].y = fmaf(p0.z, v2.y, A2[2].y);
      A2[3].x = fmaf(p0.w, v2.x, A2[3].x);  A2[3].y = fmaf(p0.w, v2.y, A2[3].y);
      A2[4].x = fmaf(p1.x, v2.x, A2[4].x);  A2[4].y = fmaf(p1.x, v2.y, A2[4].y);
      A2[5].x = fmaf(p1.y, v2.x, A2[5].x);  A2[5].y = fmaf(p1.y, v2.y, A2[5].y);
      A2[6].x = fmaf(p1.z, v2.x, A2[6].x);  A2[6].y = fmaf(p1.z, v2.y, A2[6].y);
      A2[7].x = fmaf(p1.w, v2.x, A2[7].x);  A2[7].y = fmaf(p1.w, v2.y, A2[7].y);
    }
  }

  // ---- in-block combine
  __syncthreads();
  if (cq == 0 && rq == 0) {
    *(float2*)&ml[w * 16 + hq * 2] = make_float2(m_run[0], m_run[1]);
    *(float2*)&ml[64 + w * 16 + hq * 2] = make_float2(l_run[0], l_run[1]);
  }
  __syncthreads();
  float ew[8];
  #pragma unroll
  for (int h = 0; h < 8; ++h) {
    const float ms = fmaxf(fmaxf(ml[h], ml[16 + h]), fmaxf(ml[32 + h], ml[48 + h]));
    ew[h] = __expf(ml[w * 16 + h] - ms);
  }
  float* Aw = &kbw[0][0];  // 8 x 132 (spans kbw[0..1], dead after loop)
  for (int step = 0; step < 4; ++step) {
    if (w == step) {
      #pragma unroll
      for (int h = 0; h < 8; ++h) {
        float2 x;
        if (step == 0) {
          x = make_float2(ew[h] * A2[h].x, ew[h] * A2[h].y);
        } else {
          x = *(const float2*)&Aw[h * 132 + lane * 2];
          x.x = fmaf(ew[h], A2[h].x, x.x);
          x.y = fmaf(ew[h], A2[h].y, x.y);
        }
        *(float2*)&Aw[h * 132 + lane * 2] = x;
      }
    }
    __syncthreads();
  }
  const size_t cb = (size_t)(b * 4 + y) * NCHc + bx;
  {
    const int hh = t >> 5, d4c = t & 31;
    *(float4*)&pacc[cb * 1024 + (size_t)hh * Dz + d4c * 4] =
        *(const float4*)&Aw[hh * 132 + d4c * 4];
  }
  if (t < 8) {
    const int hh = t;
    const float m0 = ml[hh], m1 = ml[16 + hh], m2 = ml[32 + hh], m3 = ml[48 + hh];
    const float msf = fmaxf(fmaxf(m0, m1), fmaxf(m2, m3));
    const float l = __expf(m0 - msf) * ml[64 + hh] + __expf(m1 - msf) * ml[80 + hh] +
                    __expf(m2 - msf) * ml[96 + hh] + __expf(m3 - msf) * ml[112 + hh];
    mbuf[cb * 8 + hh] = msf;
    lbuf[cb * 8 + hh] = l;
  }
#undef STAGE
}

// ---------------- combine chunk partials -> ctx (B, H*D); grid Bz*4, block 512
__global__ __launch_bounds__(512) void attn_combine(
    const float* __restrict__ mbuf, const float* __restrict__ lbuf,
    const float* __restrict__ pacc, const int* __restrict__ positions,
    float* __restrict__ ctx) {
  const int bgH = blockIdx.x;          // b*4 + y
  const int b = bgH >> 2, y = bgH & 3;
  const int t = threadIdx.x;
  const int h = t >> 6, dg = t & 63;   // head 0..7, d-pair 0..63
  float mstar = -1e30f;
  for (int c = 0; c < NCHc; c++) mstar = fmaxf(mstar, mbuf[((size_t)bgH * NCHc + c) * 8 + h]);
  float lsum = 0.f;
  float2 A = make_float2(0.f, 0.f);
  for (int c = 0; c < NCHc; c++) {
    const size_t cb = (size_t)bgH * NCHc + c;
    const float wv = __expf(mbuf[cb * 8 + h] - mstar);
    lsum += wv * lbuf[cb * 8 + h];
    const float2 p = *(const float2*)&pacc[cb * 1024 + (size_t)h * Dz + dg * 2];
    A.x = fmaf(wv, p.x, A.x);
    A.y = fmaf(wv, p.y, A.y);
  }
  const float inv = 1.0f / lsum;
  float2 o = make_float2(A.x * inv, A.y * inv);
  *(float2*)&ctx[(size_t)b * (Hz * Dz) + (y * 8 + h) * Dz + dg * 2] = o;
}

// ---------------- reduce dense partials -> out
__global__ __launch_bounds__(256) void reduce_out(
    const float* __restrict__ part, float* __restrict__ out, int KT) {
  const int idx = blockIdx.x * 256 + threadIdx.x;
  const int b = idx >> 12;
  const int j = idx & 4095;
  float s = 0.f;
  for (int kt = 0; kt < KT; kt++) s += part[((size_t)kt * Bz + b) * HIDz + j];
  out[idx] = s;
}

extern "C" void kernel_launch(void* const* d_in, const int* in_sizes, int n_in,
                              void* d_out, int out_size, void* d_ws, size_t ws_size,
                              hipStream_t stream) {
  const float* hidden = (const float*)d_in[0];
  const int* positions = (const int*)d_in[1];
  const float* kcache = (const float*)d_in[2];
  const float* vcache = (const float*)d_in[3];
  const float* Wqkv = (const float*)d_in[4];
  const float* bqkv = (const float*)d_in[5];
  const float* Wd = (const float*)d_in[6];
  float* out = (float*)d_out;

  const int KT = KTs;
  const int KH = HIDz / KT;

  float* w = (float*)d_ws;
  float* p1 = w;    w += (size_t)KT * Bz * QKVz;
  float* qrot = w;  w += (size_t)Bz * Hz * Dz;
  float* krot = w;  w += (size_t)Bz * Gz * Dz;
  float* vnew = w;  w += (size_t)Bz * Gz * Dz;
  float* mbuf = w;  w += (size_t)Bz * 4 * NCHc * 8;
  float* lbuf = w;  w += (size_t)Bz * 4 * NCHc * 8;
  float* pacc = w;  w += (size_t)Bz * 4 * NCHc * 1024;
  float* ctx = w;

  const size_t smem = (size_t)Bz * (KH + 4) * sizeof(float);

  gemm_partial<<<dim3(QKVz / 64, KT), 256, smem, stream>>>(hidden, Wqkv, p1, HIDz, QKVz, KH);
  qkv_finish<<<dim3(Bz, 9), 256, 0, stream>>>(p1, bqkv, positions, KT, qrot, krot, vnew);
  attn_unit<<<dim3(NCHc, 4, Bz), 256, 0, stream>>>(qrot, kcache, vcache, krot, vnew, positions,
                                                   mbuf, lbuf, pacc);
  attn_combine<<<dim3(Bz * 4), 512, 0, stream>>>(mbuf, lbuf, pacc, positions, ctx);
  gemm_partial<<<dim3(HIDz / 64, KT), 256, smem, stream>>>(ctx, Wd, p1, Hz * Dz, HIDz, KH);
  reduce_out<<<dim3(Bz * HIDz / 256), 256, 0, stream>>>(p1, out, KT);
}

// Round 21
// 154.479 us; speedup vs baseline: 1.1707x; 1.1707x over previous
//
#include <hip/hip_runtime.h>
#include <math.h>

#define Bz 32
#define Sz 4096
#define Hz 32
#define Gz 2
#define Dz 128
#define HIDz 4096
#define QKVz 4608
#define NCHc 32   // combine chunks per (b,y) = blocks; block span <= 128 rows

static __device__ __forceinline__ void fma4(float4& a, float s, const float4& v) {
  a.x = fmaf(s, v.x, a.x);
  a.y = fmaf(s, v.y, a.y);
  a.z = fmaf(s, v.z, a.z);
  a.w = fmaf(s, v.w, a.w);
}
static __device__ __forceinline__ float dot4(const float4& a, const float4& b, float acc) {
  return fmaf(a.x, b.x, fmaf(a.y, b.y, fmaf(a.z, b.z, fmaf(a.w, b.w, acc))));
}
// direct HBM->LDS, 16 B per lane (wave-uniform LDS base + lane*16 by construction)
static __device__ __forceinline__ void gload16(const float* src, float* ldst) {
  __builtin_amdgcn_global_load_lds(
      (const __attribute__((address_space(1))) void*)src,
      (__attribute__((address_space(3))) void*)ldst, 16, 0, 0);
}

// ---------------- split-K GEMM partial: part[kt][b][j] = sum_{k in chunk} X[b][k]*W[k][j]
// grid (N/128, KT), block 256. Thread: 4 j-cols x 4 b-rows. 2-deep 4-row W pipeline.
__global__ __launch_bounds__(256) void gemm_partial(
    const float* __restrict__ X, const float* __restrict__ W,
    float* __restrict__ part, int K, int N, int KH) {
  extern __shared__ float hl[];  // [32][KH+4]
  const int stride = KH + 4;
  const int t = threadIdx.x;
  const int k0 = blockIdx.y * KH;
  const int cols4 = KH >> 2;
  const int total4 = Bz * cols4;
  for (int fi = t; fi < total4; fi += 256) {
    const int row = fi / cols4;
    const int c4 = fi - row * cols4;
    const float4 v = *(const float4*)&X[(size_t)row * K + k0 + c4 * 4];
    *(float4*)&hl[row * stride + c4 * 4] = v;
  }
  __syncthreads();
  const int jl = t & 31;
  const int b0 = (t >> 5) * 4;
  const int j = blockIdx.x * 128 + jl * 4;
  float4 acc[4];
  #pragma unroll
  for (int i = 0; i < 4; i++) acc[i] = make_float4(0.f, 0.f, 0.f, 0.f);
  float4 wa[4], wb[4];
#define LDW(buf, kk)                                                      \
  { _Pragma("unroll") for (int r = 0; r < 4; ++r)                         \
      buf[r] = *(const float4*)&W[(size_t)(k0 + (kk) + r) * N + j]; }
#define FMAW(buf, kk)                                                     \
  { _Pragma("unroll") for (int bi = 0; bi < 4; ++bi) {                    \
      const float4 hb = *(const float4*)&hl[(b0 + bi) * stride + (kk)];   \
      fma4(acc[bi], hb.x, buf[0]);                                        \
      fma4(acc[bi], hb.y, buf[1]);                                        \
      fma4(acc[bi], hb.z, buf[2]);                                        \
      fma4(acc[bi], hb.w, buf[3]); } }
  LDW(wa, 0);
  for (int kk = 0; kk < KH; kk += 8) {
    LDW(wb, kk + 4);
    FMAW(wa, kk);
    if (kk + 8 < KH) LDW(wa, kk + 8);
    FMAW(wb, kk + 4);
  }
#undef LDW
#undef FMAW
  #pragma unroll
  for (int bi = 0; bi < 4; bi++) {
    *(float4*)&part[((size_t)blockIdx.y * Bz + b0 + bi) * N + j] = acc[bi];
  }
}

// ---------------- reduce QKV partials + bias, RoPE, emit qrot (pre-scaled), krot, vnew
__global__ __launch_bounds__(256) void qkv_finish(
    const float* __restrict__ part, const float* __restrict__ bias,
    const int* __restrict__ positions, int KT,
    float* __restrict__ qrot, float* __restrict__ krot, float* __restrict__ vnew) {
  const int t = threadIdx.x;
  const int b = blockIdx.x;
  const int head = blockIdx.y * 4 + (t >> 6);
  const int tp = t & 63;
  const int j0 = head * Dz + tp * 2;
  float s0 = bias[j0];
  float s1 = bias[j0 + 1];
  for (int kt = 0; kt < KT; kt++) {
    const float2 p = *(const float2*)&part[((size_t)kt * Bz + b) * QKVz + j0];
    s0 += p.x;
    s1 += p.y;
  }
  float o0 = s0, o1 = s1;
  if (head < Hz + Gz && tp < 32) {
    const float invf = exp2f(-(float)tp * (13.287712379549449f / 32.0f));
    const float a = (float)positions[b] * invf;
    float sn, cs;
    sincosf(a, &sn, &cs);
    o0 = s0 * cs - s1 * sn;
    o1 = s1 * cs + s0 * sn;
  }
  if (head < Hz) {
    const float sc = 0.08838834764831845f;
    float2 o = make_float2(o0 * sc, o1 * sc);
    *(float2*)&qrot[((size_t)b * Hz + head) * Dz + tp * 2] = o;
  } else if (head < Hz + Gz) {
    float2 o = make_float2(o0, o1);
    *(float2*)&krot[((size_t)b * Gz + (head - Hz)) * Dz + tp * 2] = o;
  } else {
    float2 o = make_float2(s0, s1);
    *(float2*)&vnew[((size_t)b * Gz + (head - Hz - Gz)) * Dz + tp * 2] = o;
  }
}

// ---------------- flash block (8 heads): y = blockIdx.y in [0,4): heads y*8..y*8+7,
// KV group g = y>>1. Block bx owns span [bx*(pos+1)/32, (bx+1)*(pos+1)/32) (<=128 rows).
// Wave w owns rows [w*8, w*8+8) of each 32-row tile, stages its K rows via global_load_lds
// into a wave-private single buffer (no barriers in loop). QK lane (hq,rq,cq): 2 heads
// x 4 rows, Q in registers; reduce over 8 cq lanes. PV lane = d-pair: V direct from
// global; P via wave LDS. ~84 VGPR; cap 128 (256,2) -> NO spill; 4 blocks/CU.
__global__ __launch_bounds__(256, 2) void attn_unit(
    const float* __restrict__ qrot, const float* __restrict__ kcache,
    const float* __restrict__ vcache, const float* __restrict__ krot,
    const float* __restrict__ vnew, const int* __restrict__ positions,
    float* __restrict__ mbuf, float* __restrict__ lbuf, float* __restrict__ pacc) {
  __shared__ float qs[8 * 132];  // Q staging [h 0..7][c4*4], stride 132
  __shared__ float kbw[4][1024]; // per-wave K buffer (8 rows x 128); aliased as Aw
  __shared__ float plw[4][64];   // per-wave P: [s 0..7][h 0..7]
  __shared__ float scw[4][8];    // per-wave rescale factors
  __shared__ float ml[128];      // m: [w*16+h], l: [64 + w*16+h]
  const int y = blockIdx.y, b = blockIdx.z, bx = blockIdx.x;
  const int g = y >> 1;
  const int pos = positions[b];
  const int lt = pos + 1;
  const int blo = (bx * lt) >> 5;
  const int bhi = ((bx + 1) * lt) >> 5;
  const int nr = bhi - blo;
  const int t = threadIdx.x, w = t >> 6, lane = t & 63;
  const int hq = lane >> 4, rq = (lane >> 3) & 1, cq = lane & 7;
  float* kw = kbw[w];
  float* plv = plw[w];

  // Q tile -> LDS once (pre-scaled). 8 heads x 32 float4 = 256 entries = 1 per thread.
  {
    const int h = t >> 5, c4 = t & 31;
    const float4 q = *(const float4*)&qrot[((size_t)b * Hz + y * 8 + h) * Dz + c4 * 4];
    *(float4*)&qs[h * 132 + c4 * 4] = q;
  }

  const float* krow_new = &krot[((size_t)b * Gz + g) * Dz];
  const float* vrow_new = &vnew[((size_t)b * Gz + g) * Dz];
  const size_t kvb = ((size_t)b * Sz) * (Gz * Dz) + (size_t)g * Dz;

#define STAGE(tile) {                                                              \
    const int sg_ = blo + (tile) * 32 + w * 8 + (lane >> 3);                       \
    const bool fr_ = (sg_ >= bhi) || (sg_ == pos);                                 \
    const float* kp_ = fr_ ? krow_new : &kcache[kvb + (size_t)sg_ * (Gz * Dz)];    \
    gload16(kp_ + (lane & 7) * 4,      &kw[0 * 256 + lane * 4]);                   \
    gload16(kp_ + (lane & 7) * 4 + 32, &kw[1 * 256 + lane * 4]);                   \
    gload16(kp_ + (lane & 7) * 4 + 64, &kw[2 * 256 + lane * 4]);                   \
    gload16(kp_ + (lane & 7) * 4 + 96, &kw[3 * 256 + lane * 4]); }

  float m_run[2], l_run[2];
  float2 A2[8];
  #pragma unroll
  for (int i = 0; i < 2; ++i) { m_run[i] = -1e30f; l_run[i] = 0.f; }
  #pragma unroll
  for (int h = 0; h < 8; ++h) A2[h] = make_float2(0.f, 0.f);

  const int ntw = (nr > w * 8) ? ((nr - w * 8 + 31) >> 5) : 0;  // wave-uniform tiles
  __syncthreads();  // qs visible to all waves

  // Q into registers once per block: qr[i][j] = Q[hq*2+i][(cq + 8j)*4 ..]
  float4 qr[2][4];
  #pragma unroll
  for (int i = 0; i < 2; ++i)
    #pragma unroll
    for (int j = 0; j < 4; ++j)
      qr[i][j] = *(const float4*)&qs[(hq * 2 + i) * 132 + (cq + 8 * j) * 4];

  for (int tile = 0; tile < ntw; ++tile) {
    STAGE(tile);
    // ---- QK: K from wave LDS buffer, Q from registers
    float lp[2][4];
    #pragma unroll
    for (int i = 0; i < 2; ++i)
      #pragma unroll
      for (int s = 0; s < 4; ++s) lp[i][s] = 0.f;
    #pragma unroll
    for (int j = 0; j < 4; ++j) {
      float4 kf[4];
      #pragma unroll
      for (int s = 0; s < 4; ++s)
        kf[s] = *(const float4*)&kw[j * 256 + ((rq * 4 + s) * 8 + cq) * 4];
      #pragma unroll
      for (int i = 0; i < 2; ++i) {
        #pragma unroll
        for (int s = 0; s < 4; ++s) lp[i][s] = dot4(qr[i][j], kf[s], lp[i][s]);
      }
    }
    // reduce over cq lanes
    #pragma unroll
    for (int i = 0; i < 2; ++i)
      #pragma unroll
      for (int s = 0; s < 4; ++s) {
        lp[i][s] += __shfl_xor(lp[i][s], 1);
        lp[i][s] += __shfl_xor(lp[i][s], 2);
        lp[i][s] += __shfl_xor(lp[i][s], 4);
      }
    // mask rows beyond span
    const int rbase = tile * 32 + w * 8 + rq * 4;
    #pragma unroll
    for (int s = 0; s < 4; ++s) {
      if (rbase + s >= nr) {
        lp[0][s] = -1e30f;
        lp[1][s] = -1e30f;
      }
    }
    // ---- online softmax per head
    float sc[2];
    #pragma unroll
    for (int i = 0; i < 2; ++i) {
      float tm = fmaxf(fmaxf(lp[i][0], lp[i][1]), fmaxf(lp[i][2], lp[i][3]));
      tm = fmaxf(tm, __shfl_xor(tm, 8));
      const float mn = fmaxf(m_run[i], tm);
      sc[i] = __expf(m_run[i] - mn);
      m_run[i] = mn;
      float ts = 0.f;
      #pragma unroll
      for (int s = 0; s < 4; ++s) {
        lp[i][s] = __expf(lp[i][s] - mn);
        ts += lp[i][s];
      }
      ts += __shfl_xor(ts, 8);
      l_run[i] = l_run[i] * sc[i] + ts;
    }
    // ---- handoff P and sc (wave-private LDS; same-wave ordering)
    if (cq == 0) {
      if (rq == 0) *(float2*)&scw[w][hq * 2] = make_float2(sc[0], sc[1]);
      #pragma unroll
      for (int s = 0; s < 4; ++s)
        *(float2*)&plv[(rq * 4 + s) * 8 + hq * 2] = make_float2(lp[0][s], lp[1][s]);
    }
    // ---- PV: rescale A2, then accumulate (V direct from global, coalesced)
    {
      const float4 s0 = *(const float4*)&scw[w][0];
      const float4 s1 = *(const float4*)&scw[w][4];
      A2[0].x *= s0.x; A2[0].y *= s0.x;  A2[1].x *= s0.y; A2[1].y *= s0.y;
      A2[2].x *= s0.z; A2[2].y *= s0.z;  A2[3].x *= s0.w; A2[3].y *= s0.w;
      A2[4].x *= s1.x; A2[4].y *= s1.x;  A2[5].x *= s1.y; A2[5].y *= s1.y;
      A2[6].x *= s1.z; A2[6].y *= s1.z;  A2[7].x *= s1.w; A2[7].y *= s1.w;
    }
    #pragma unroll
    for (int s = 0; s < 8; ++s) {
      const int sg = blo + tile * 32 + w * 8 + s;          // wave-uniform
      const float* vp = (sg >= bhi || sg == pos) ? vrow_new
                         : &vcache[kvb + (size_t)sg * (Gz * Dz)];
      const float2 v2 = *(const float2*)&vp[lane * 2];
      const float4 p0 = *(const float4*)&plv[s * 8 + 0];
      const float4 p1 = *(const float4*)&plv[s * 8 + 4];
      A2[0].x = fmaf(p0.x, v2.x, A2[0].x);  A2[0].y = fmaf(p0.x, v2.y, A2[0].y);
      A2[1].x = fmaf(p0.y, v2.x, A2[1].x);  A2[1].y = fmaf(p0.y, v2.y, A2[1].y);
      A2[2].x = fmaf(p0.z, v2.x, A2[2].x);  A2[2].y = fmaf(p0.z, v2.y, A2[2].y);
      A2[3].x = fmaf(p0.w, v2.x, A2[3].x);  A2[3].y = fmaf(p0.w, v2.y, A2[3].y);
      A2[4].x = fmaf(p1.x, v2.x, A2[4].x);  A2[4].y = fmaf(p1.x, v2.y, A2[4].y);
      A2[5].x = fmaf(p1.y, v2.x, A2[5].x);  A2[5].y = fmaf(p1.y, v2.y, A2[5].y);
      A2[6].x = fmaf(p1.z, v2.x, A2[6].x);  A2[6].y = fmaf(p1.z, v2.y, A2[6].y);
      A2[7].x = fmaf(p1.w, v2.x, A2[7].x);  A2[7].y = fmaf(p1.w, v2.y, A2[7].y);
    }
  }

  // ---- in-block combine
  __syncthreads();
  if (cq == 0 && rq == 0) {
    *(float2*)&ml[w * 16 + hq * 2] = make_float2(m_run[0], m_run[1]);
    *(float2*)&ml[64 + w * 16 + hq * 2] = make_float2(l_run[0], l_run[1]);
  }
  __syncthreads();
  float ew[8];
  #pragma unroll
  for (int h = 0; h < 8; ++h) {
    const float ms = fmaxf(fmaxf(ml[h], ml[16 + h]), fmaxf(ml[32 + h], ml[48 + h]));
    ew[h] = __expf(ml[w * 16 + h] - ms);
  }
  float* Aw = &kbw[0][0];  // 8 x 132 (spans kbw[0..1], dead after loop)
  for (int step = 0; step < 4; ++step) {
    if (w == step) {
      #pragma unroll
      for (int h = 0; h < 8; ++h) {
        float2 x;
        if (step == 0) {
          x = make_float2(ew[h] * A2[h].x, ew[h] * A2[h].y);
        } else {
          x = *(const float2*)&Aw[h * 132 + lane * 2];
          x.x = fmaf(ew[h], A2[h].x, x.x);
          x.y = fmaf(ew[h], A2[h].y, x.y);
        }
        *(float2*)&Aw[h * 132 + lane * 2] = x;
      }
    }
    __syncthreads();
  }
  const size_t cb = (size_t)(b * 4 + y) * NCHc + bx;
  {
    const int hh = t >> 5, d4c = t & 31;
    *(float4*)&pacc[cb * 1024 + (size_t)hh * Dz + d4c * 4] =
        *(const float4*)&Aw[hh * 132 + d4c * 4];
  }
  if (t < 8) {
    const int hh = t;
    const float m0 = ml[hh], m1 = ml[16 + hh], m2 = ml[32 + hh], m3 = ml[48 + hh];
    const float msf = fmaxf(fmaxf(m0, m1), fmaxf(m2, m3));
    const float l = __expf(m0 - msf) * ml[64 + hh] + __expf(m1 - msf) * ml[80 + hh] +
                    __expf(m2 - msf) * ml[96 + hh] + __expf(m3 - msf) * ml[112 + hh];
    mbuf[cb * 8 + hh] = msf;
    lbuf[cb * 8 + hh] = l;
  }
#undef STAGE
}

// ---------------- combine chunk partials -> ctx (B, H*D); grid Bz*4, block 512
__global__ __launch_bounds__(512) void attn_combine(
    const float* __restrict__ mbuf, const float* __restrict__ lbuf,
    const float* __restrict__ pacc, const int* __restrict__ positions,
    float* __restrict__ ctx) {
  const int bgH = blockIdx.x;          // b*4 + y
  const int b = bgH >> 2, y = bgH & 3;
  const int t = threadIdx.x;
  const int h = t >> 6, dg = t & 63;   // head 0..7, d-pair 0..63
  float mstar = -1e30f;
  for (int c = 0; c < NCHc; c++) mstar = fmaxf(mstar, mbuf[((size_t)bgH * NCHc + c) * 8 + h]);
  float lsum = 0.f;
  float2 A = make_float2(0.f, 0.f);
  for (int c = 0; c < NCHc; c++) {
    const size_t cb = (size_t)bgH * NCHc + c;
    const float wv = __expf(mbuf[cb * 8 + h] - mstar);
    lsum += wv * lbuf[cb * 8 + h];
    const float2 p = *(const float2*)&pacc[cb * 1024 + (size_t)h * Dz + dg * 2];
    A.x = fmaf(wv, p.x, A.x);
    A.y = fmaf(wv, p.y, A.y);
  }
  const float inv = 1.0f / lsum;
  float2 o = make_float2(A.x * inv, A.y * inv);
  *(float2*)&ctx[(size_t)b * (Hz * Dz) + (y * 8 + h) * Dz + dg * 2] = o;
}

// ---------------- reduce dense partials -> out
__global__ __launch_bounds__(256) void reduce_out(
    const float* __restrict__ part, float* __restrict__ out, int KT) {
  const int idx = blockIdx.x * 256 + threadIdx.x;
  const int b = idx >> 12;
  const int j = idx & 4095;
  float s = 0.f;
  for (int kt = 0; kt < KT; kt++) s += part[((size_t)kt * Bz + b) * HIDz + j];
  out[idx] = s;
}

extern "C" void kernel_launch(void* const* d_in, const int* in_sizes, int n_in,
                              void* d_out, int out_size, void* d_ws, size_t ws_size,
                              hipStream_t stream) {
  const float* hidden = (const float*)d_in[0];
  const int* positions = (const int*)d_in[1];
  const float* kcache = (const float*)d_in[2];
  const float* vcache = (const float*)d_in[3];
  const float* Wqkv = (const float*)d_in[4];
  const float* bqkv = (const float*)d_in[5];
  const float* Wd = (const float*)d_in[6];
  float* out = (float*)d_out;

  auto need = [](int KT) -> size_t {
    return (size_t)KT * Bz * QKVz
         + (size_t)Bz * Hz * Dz
         + (size_t)Bz * Gz * Dz * 2
         + (size_t)Bz * 4 * NCHc * 8 * 2
         + (size_t)Bz * 4 * NCHc * 1024
         + (size_t)Bz * HIDz;
  };
  int KT = 32;
  if (need(32) * sizeof(float) > ws_size) KT = 16;
  const int KH = HIDz / KT;

  float* w = (float*)d_ws;
  float* p1 = w;    w += (size_t)KT * Bz * QKVz;
  float* qrot = w;  w += (size_t)Bz * Hz * Dz;
  float* krot = w;  w += (size_t)Bz * Gz * Dz;
  float* vnew = w;  w += (size_t)Bz * Gz * Dz;
  float* mbuf = w;  w += (size_t)Bz * 4 * NCHc * 8;
  float* lbuf = w;  w += (size_t)Bz * 4 * NCHc * 8;
  float* pacc = w;  w += (size_t)Bz * 4 * NCHc * 1024;
  float* ctx = w;

  const size_t smem = (size_t)Bz * (KH + 4) * sizeof(float);

  gemm_partial<<<dim3(QKVz / 128, KT), 256, smem, stream>>>(hidden, Wqkv, p1, HIDz, QKVz, KH);
  qkv_finish<<<dim3(Bz, 9), 256, 0, stream>>>(p1, bqkv, positions, KT, qrot, krot, vnew);
  attn_unit<<<dim3(NCHc, 4, Bz), 256, 0, stream>>>(qrot, kcache, vcache, krot, vnew, positions,
                                                   mbuf, lbuf, pacc);
  attn_combine<<<dim3(Bz * 4), 512, 0, stream>>>(mbuf, lbuf, pacc, positions, ctx);
  gemm_partial<<<dim3(HIDz / 128, KT), 256, smem, stream>>>(ctx, Wd, p1, Hz * Dz, HIDz, KH);
  reduce_out<<<dim3(Bz * HIDz / 256), 256, 0, stream>>>(p1, out, KT);
}

// Round 22
// 150.868 us; speedup vs baseline: 1.1987x; 1.0239x over previous
//
#include <hip/hip_runtime.h>
#include <math.h>

#define Bz 32
#define Sz 4096
#define Hz 32
#define Gz 2
#define Dz 128
#define HIDz 4096
#define QKVz 4608
#define NCHc 32   // combine chunks per (b,y) = blocks; block span <= 128 rows
#define KTs 16    // split-K factor for both GEMMs

static __device__ __forceinline__ void fma4(float4& a, float s, const float4& v) {
  a.x = fmaf(s, v.x, a.x);
  a.y = fmaf(s, v.y, a.y);
  a.z = fmaf(s, v.z, a.z);
  a.w = fmaf(s, v.w, a.w);
}
static __device__ __forceinline__ float dot4(const float4& a, const float4& b, float acc) {
  return fmaf(a.x, b.x, fmaf(a.y, b.y, fmaf(a.z, b.z, fmaf(a.w, b.w, acc))));
}
// direct HBM->LDS, 16 B per lane (wave-uniform LDS base + lane*16 by construction)
static __device__ __forceinline__ void gload16(const float* src, float* ldst) {
  __builtin_amdgcn_global_load_lds(
      (const __attribute__((address_space(1))) void*)src,
      (__attribute__((address_space(3))) void*)ldst, 16, 0, 0);
}

// ---------------- split-K GEMM partial: part[kt][b][j] = sum_{k in chunk} X[b][k]*W[k][j]
// grid (N/128, KTs), block 256. Thread: 4 j-cols x 4 b-rows. 4-deep 4-row W pipeline
// (16 loads in flight per wave -> ~9 KB/CU outstanding, ~2.6 TB/s W stream).
__global__ __launch_bounds__(256) void gemm_partial(
    const float* __restrict__ X, const float* __restrict__ W,
    float* __restrict__ part, int K, int N, int KH) {
  extern __shared__ float hl[];  // [32][KH+4]
  const int stride = KH + 4;
  const int t = threadIdx.x;
  const int k0 = blockIdx.y * KH;
  const int cols4 = KH >> 2;
  const int total4 = Bz * cols4;
  for (int fi = t; fi < total4; fi += 256) {
    const int row = fi / cols4;
    const int c4 = fi - row * cols4;
    const float4 v = *(const float4*)&X[(size_t)row * K + k0 + c4 * 4];
    *(float4*)&hl[row * stride + c4 * 4] = v;
  }
  __syncthreads();
  const int jl = t & 31;
  const int b0 = (t >> 5) * 4;
  const int j = blockIdx.x * 128 + jl * 4;
  float4 acc[4];
  #pragma unroll
  for (int i = 0; i < 4; i++) acc[i] = make_float4(0.f, 0.f, 0.f, 0.f);
  float4 wa[4], wb[4], wc[4], wd[4];
#define LDW(buf, kk)                                                      \
  { _Pragma("unroll") for (int r = 0; r < 4; ++r)                         \
      buf[r] = *(const float4*)&W[(size_t)(k0 + (kk) + r) * N + j]; }
#define FMAW(buf, kk)                                                     \
  { _Pragma("unroll") for (int bi = 0; bi < 4; ++bi) {                    \
      const float4 hb = *(const float4*)&hl[(b0 + bi) * stride + (kk)];   \
      fma4(acc[bi], hb.x, buf[0]);                                        \
      fma4(acc[bi], hb.y, buf[1]);                                        \
      fma4(acc[bi], hb.z, buf[2]);                                        \
      fma4(acc[bi], hb.w, buf[3]); } }
  LDW(wa, 0);
  LDW(wb, 4);
  LDW(wc, 8);
  LDW(wd, 12);
  for (int kk = 0; kk < KH; kk += 16) {
    FMAW(wa, kk);
    if (kk + 16 < KH) LDW(wa, kk + 16);
    FMAW(wb, kk + 4);
    if (kk + 20 < KH) LDW(wb, kk + 20);
    FMAW(wc, kk + 8);
    if (kk + 24 < KH) LDW(wc, kk + 24);
    FMAW(wd, kk + 12);
    if (kk + 28 < KH) LDW(wd, kk + 28);
  }
#undef LDW
#undef FMAW
  #pragma unroll
  for (int bi = 0; bi < 4; bi++) {
    *(float4*)&part[((size_t)blockIdx.y * Bz + b0 + bi) * N + j] = acc[bi];
  }
}

// ---------------- reduce QKV partials + bias, RoPE, emit qrot (pre-scaled), krot, vnew
__global__ __launch_bounds__(256) void qkv_finish(
    const float* __restrict__ part, const float* __restrict__ bias,
    const int* __restrict__ positions, int KT,
    float* __restrict__ qrot, float* __restrict__ krot, float* __restrict__ vnew) {
  const int t = threadIdx.x;
  const int b = blockIdx.x;
  const int head = blockIdx.y * 4 + (t >> 6);
  const int tp = t & 63;
  const int j0 = head * Dz + tp * 2;
  float s0 = bias[j0];
  float s1 = bias[j0 + 1];
  for (int kt = 0; kt < KT; kt++) {
    const float2 p = *(const float2*)&part[((size_t)kt * Bz + b) * QKVz + j0];
    s0 += p.x;
    s1 += p.y;
  }
  float o0 = s0, o1 = s1;
  if (head < Hz + Gz && tp < 32) {
    const float invf = exp2f(-(float)tp * (13.287712379549449f / 32.0f));
    const float a = (float)positions[b] * invf;
    float sn, cs;
    sincosf(a, &sn, &cs);
    o0 = s0 * cs - s1 * sn;
    o1 = s1 * cs + s0 * sn;
  }
  if (head < Hz) {
    const float sc = 0.08838834764831845f;
    float2 o = make_float2(o0 * sc, o1 * sc);
    *(float2*)&qrot[((size_t)b * Hz + head) * Dz + tp * 2] = o;
  } else if (head < Hz + Gz) {
    float2 o = make_float2(o0, o1);
    *(float2*)&krot[((size_t)b * Gz + (head - Hz)) * Dz + tp * 2] = o;
  } else {
    float2 o = make_float2(s0, s1);
    *(float2*)&vnew[((size_t)b * Gz + (head - Hz - Gz)) * Dz + tp * 2] = o;
  }
}

// ---------------- flash block (8 heads): y = blockIdx.y in [0,4): heads y*8..y*8+7,
// KV group g = y>>1. Block bx owns span [bx*(pos+1)/32, (bx+1)*(pos+1)/32) (<=128 rows).
// Wave w owns rows [w*8, w*8+8) of each 32-row tile, stages its K rows via global_load_lds
// into a wave-private single buffer (no barriers in loop). QK lane (hq,rq,cq): 2 heads
// x 4 rows, Q in registers; reduce over 8 cq lanes. PV lane = d-pair: V direct from
// global; P via wave LDS. ~84 VGPR; cap 128 (256,2) -> NO spill; 4 blocks/CU.
__global__ __launch_bounds__(256, 2) void attn_unit(
    const float* __restrict__ qrot, const float* __restrict__ kcache,
    const float* __restrict__ vcache, const float* __restrict__ krot,
    const float* __restrict__ vnew, const int* __restrict__ positions,
    float* __restrict__ mbuf, float* __restrict__ lbuf, float* __restrict__ pacc) {
  __shared__ float qs[8 * 132];  // Q staging [h 0..7][c4*4], stride 132
  __shared__ float kbw[4][1024]; // per-wave K buffer (8 rows x 128); aliased as Aw
  __shared__ float plw[4][64];   // per-wave P: [s 0..7][h 0..7]
  __shared__ float scw[4][8];    // per-wave rescale factors
  __shared__ float ml[128];      // m: [w*16+h], l: [64 + w*16+h]
  const int y = blockIdx.y, b = blockIdx.z, bx = blockIdx.x;
  const int g = y >> 1;
  const int pos = positions[b];
  const int lt = pos + 1;
  const int blo = (bx * lt) >> 5;
  const int bhi = ((bx + 1) * lt) >> 5;
  const int nr = bhi - blo;
  const int t = threadIdx.x, w = t >> 6, lane = t & 63;
  const int hq = lane >> 4, rq = (lane >> 3) & 1, cq = lane & 7;
  float* kw = kbw[w];
  float* plv = plw[w];

  // Q tile -> LDS once (pre-scaled). 8 heads x 32 float4 = 256 entries = 1 per thread.
  {
    const int h = t >> 5, c4 = t & 31;
    const float4 q = *(const float4*)&qrot[((size_t)b * Hz + y * 8 + h) * Dz + c4 * 4];
    *(float4*)&qs[h * 132 + c4 * 4] = q;
  }

  const float* krow_new = &krot[((size_t)b * Gz + g) * Dz];
  const float* vrow_new = &vnew[((size_t)b * Gz + g) * Dz];
  const size_t kvb = ((size_t)b * Sz) * (Gz * Dz) + (size_t)g * Dz;

#define STAGE(tile) {                                                              \
    const int sg_ = blo + (tile) * 32 + w * 8 + (lane >> 3);                       \
    const bool fr_ = (sg_ >= bhi) || (sg_ == pos);                                 \
    const float* kp_ = fr_ ? krow_new : &kcache[kvb + (size_t)sg_ * (Gz * Dz)];    \
    gload16(kp_ + (lane & 7) * 4,      &kw[0 * 256 + lane * 4]);                   \
    gload16(kp_ + (lane & 7) * 4 + 32, &kw[1 * 256 + lane * 4]);                   \
    gload16(kp_ + (lane & 7) * 4 + 64, &kw[2 * 256 + lane * 4]);                   \
    gload16(kp_ + (lane & 7) * 4 + 96, &kw[3 * 256 + lane * 4]); }

  float m_run[2], l_run[2];
  float2 A2[8];
  #pragma unroll
  for (int i = 0; i < 2; ++i) { m_run[i] = -1e30f; l_run[i] = 0.f; }
  #pragma unroll
  for (int h = 0; h < 8; ++h) A2[h] = make_float2(0.f, 0.f);

  const int ntw = (nr > w * 8) ? ((nr - w * 8 + 31) >> 5) : 0;  // wave-uniform tiles
  __syncthreads();  // qs visible to all waves

  // Q into registers once per block: qr[i][j] = Q[hq*2+i][(cq + 8j)*4 ..]
  float4 qr[2][4];
  #pragma unroll
  for (int i = 0; i < 2; ++i)
    #pragma unroll
    for (int j = 0; j < 4; ++j)
      qr[i][j] = *(const float4*)&qs[(hq * 2 + i) * 132 + (cq + 8 * j) * 4];

  for (int tile = 0; tile < ntw; ++tile) {
    STAGE(tile);
    // ---- QK: K from wave LDS buffer, Q from registers
    float lp[2][4];
    #pragma unroll
    for (int i = 0; i < 2; ++i)
      #pragma unroll
      for (int s = 0; s < 4; ++s) lp[i][s] = 0.f;
    #pragma unroll
    for (int j = 0; j < 4; ++j) {
      float4 kf[4];
      #pragma unroll
      for (int s = 0; s < 4; ++s)
        kf[s] = *(const float4*)&kw[j * 256 + ((rq * 4 + s) * 8 + cq) * 4];
      #pragma unroll
      for (int i = 0; i < 2; ++i) {
        #pragma unroll
        for (int s = 0; s < 4; ++s) lp[i][s] = dot4(qr[i][j], kf[s], lp[i][s]);
      }
    }
    // reduce over cq lanes
    #pragma unroll
    for (int i = 0; i < 2; ++i)
      #pragma unroll
      for (int s = 0; s < 4; ++s) {
        lp[i][s] += __shfl_xor(lp[i][s], 1);
        lp[i][s] += __shfl_xor(lp[i][s], 2);
        lp[i][s] += __shfl_xor(lp[i][s], 4);
      }
    // mask rows beyond span
    const int rbase = tile * 32 + w * 8 + rq * 4;
    #pragma unroll
    for (int s = 0; s < 4; ++s) {
      if (rbase + s >= nr) {
        lp[0][s] = -1e30f;
        lp[1][s] = -1e30f;
      }
    }
    // ---- online softmax per head
    float sc[2];
    #pragma unroll
    for (int i = 0; i < 2; ++i) {
      float tm = fmaxf(fmaxf(lp[i][0], lp[i][1]), fmaxf(lp[i][2], lp[i][3]));
      tm = fmaxf(tm, __shfl_xor(tm, 8));
      const float mn = fmaxf(m_run[i], tm);
      sc[i] = __expf(m_run[i] - mn);
      m_run[i] = mn;
      float ts = 0.f;
      #pragma unroll
      for (int s = 0; s < 4; ++s) {
        lp[i][s] = __expf(lp[i][s] - mn);
        ts += lp[i][s];
      }
      ts += __shfl_xor(ts, 8);
      l_run[i] = l_run[i] * sc[i] + ts;
    }
    // ---- handoff P and sc (wave-private LDS; same-wave ordering)
    if (cq == 0) {
      if (rq == 0) *(float2*)&scw[w][hq * 2] = make_float2(sc[0], sc[1]);
      #pragma unroll
      for (int s = 0; s < 4; ++s)
        *(float2*)&plv[(rq * 4 + s) * 8 + hq * 2] = make_float2(lp[0][s], lp[1][s]);
    }
    // ---- PV: rescale A2, then accumulate (V direct from global, coalesced)
    {
      const float4 s0 = *(const float4*)&scw[w][0];
      const float4 s1 = *(const float4*)&scw[w][4];
      A2[0].x *= s0.x; A2[0].y *= s0.x;  A2[1].x *= s0.y; A2[1].y *= s0.y;
      A2[2].x *= s0.z; A2[2].y *= s0.z;  A2[3].x *= s0.w; A2[3].y *= s0.w;
      A2[4].x *= s1.x; A2[4].y *= s1.x;  A2[5].x *= s1.y; A2[5].y *= s1.y;
      A2[6].x *= s1.z; A2[6].y *= s1.z;  A2[7].x *= s1.w; A2[7].y *= s1.w;
    }
    #pragma unroll
    for (int s = 0; s < 8; ++s) {
      const int sg = blo + tile * 32 + w * 8 + s;          // wave-uniform
      const float* vp = (sg >= bhi || sg == pos) ? vrow_new
                         : &vcache[kvb + (size_t)sg * (Gz * Dz)];
      const float2 v2 = *(const float2*)&vp[lane * 2];
      const float4 p0 = *(const float4*)&plv[s * 8 + 0];
      const float4 p1 = *(const float4*)&plv[s * 8 + 4];
      A2[0].x = fmaf(p0.x, v2.x, A2[0].x);  A2[0].y = fmaf(p0.x, v2.y, A2[0].y);
      A2[1].x = fmaf(p0.y, v2.x, A2[1].x);  A2[1].y = fmaf(p0.y, v2.y, A2[1].y);
      A2[2].x = fmaf(p0.z, v2.x, A2[2].x);  A2[2].y = fmaf(p0.z, v2.y, A2[2].y);
      A2[3].x = fmaf(p0.w, v2.x, A2[3].x);  A2[3].y = fmaf(p0.w, v2.y, A2[3].y);
      A2[4].x = fmaf(p1.x, v2.x, A2[4].x);  A2[4].y = fmaf(p1.x, v2.y, A2[4].y);
      A2[5].x = fmaf(p1.y, v2.x, A2[5].x);  A2[5].y = fmaf(p1.y, v2.y, A2[5].y);
      A2[6].x = fmaf(p1.z, v2.x, A2[6].x);  A2[6].y = fmaf(p1.z, v2.y, A2[6].y);
      A2[7].x = fmaf(p1.w, v2.x, A2[7].x);  A2[7].y = fmaf(p1.w, v2.y, A2[7].y);
    }
  }

  // ---- in-block combine
  __syncthreads();
  if (cq == 0 && rq == 0) {
    *(float2*)&ml[w * 16 + hq * 2] = make_float2(m_run[0], m_run[1]);
    *(float2*)&ml[64 + w * 16 + hq * 2] = make_float2(l_run[0], l_run[1]);
  }
  __syncthreads();
  float ew[8];
  #pragma unroll
  for (int h = 0; h < 8; ++h) {
    const float ms = fmaxf(fmaxf(ml[h], ml[16 + h]), fmaxf(ml[32 + h], ml[48 + h]));
    ew[h] = __expf(ml[w * 16 + h] - ms);
  }
  float* Aw = &kbw[0][0];  // 8 x 132 (spans kbw[0..1], dead after loop)
  for (int step = 0; step < 4; ++step) {
    if (w == step) {
      #pragma unroll
      for (int h = 0; h < 8; ++h) {
        float2 x;
        if (step == 0) {
          x = make_float2(ew[h] * A2[h].x, ew[h] * A2[h].y);
        } else {
          x = *(const float2*)&Aw[h * 132 + lane * 2];
          x.x = fmaf(ew[h], A2[h].x, x.x);
          x.y = fmaf(ew[h], A2[h].y, x.y);
        }
        *(float2*)&Aw[h * 132 + lane * 2] = x;
      }
    }
    __syncthreads();
  }
  const size_t cb = (size_t)(b * 4 + y) * NCHc + bx;
  {
    const int hh = t >> 5, d4c = t & 31;
    *(float4*)&pacc[cb * 1024 + (size_t)hh * Dz + d4c * 4] =
        *(const float4*)&Aw[hh * 132 + d4c * 4];
  }
  if (t < 8) {
    const int hh = t;
    const float m0 = ml[hh], m1 = ml[16 + hh], m2 = ml[32 + hh], m3 = ml[48 + hh];
    const float msf = fmaxf(fmaxf(m0, m1), fmaxf(m2, m3));
    const float l = __expf(m0 - msf) * ml[64 + hh] + __expf(m1 - msf) * ml[80 + hh] +
                    __expf(m2 - msf) * ml[96 + hh] + __expf(m3 - msf) * ml[112 + hh];
    mbuf[cb * 8 + hh] = msf;
    lbuf[cb * 8 + hh] = l;
  }
#undef STAGE
}

// ---------------- combine chunk partials -> ctx (B, H*D); grid Bz*4, block 512
__global__ __launch_bounds__(512) void attn_combine(
    const float* __restrict__ mbuf, const float* __restrict__ lbuf,
    const float* __restrict__ pacc, const int* __restrict__ positions,
    float* __restrict__ ctx) {
  const int bgH = blockIdx.x;          // b*4 + y
  const int b = bgH >> 2, y = bgH & 3;
  const int t = threadIdx.x;
  const int h = t >> 6, dg = t & 63;   // head 0..7, d-pair 0..63
  float mstar = -1e30f;
  for (int c = 0; c < NCHc; c++) mstar = fmaxf(mstar, mbuf[((size_t)bgH * NCHc + c) * 8 + h]);
  float lsum = 0.f;
  float2 A = make_float2(0.f, 0.f);
  for (int c = 0; c < NCHc; c++) {
    const size_t cb = (size_t)bgH * NCHc + c;
    const float wv = __expf(mbuf[cb * 8 + h] - mstar);
    lsum += wv * lbuf[cb * 8 + h];
    const float2 p = *(const float2*)&pacc[cb * 1024 + (size_t)h * Dz + dg * 2];
    A.x = fmaf(wv, p.x, A.x);
    A.y = fmaf(wv, p.y, A.y);
  }
  const float inv = 1.0f / lsum;
  float2 o = make_float2(A.x * inv, A.y * inv);
  *(float2*)&ctx[(size_t)b * (Hz * Dz) + (y * 8 + h) * Dz + dg * 2] = o;
}

// ---------------- reduce dense partials -> out
__global__ __launch_bounds__(256) void reduce_out(
    const float* __restrict__ part, float* __restrict__ out, int KT) {
  const int idx = blockIdx.x * 256 + threadIdx.x;
  const int b = idx >> 12;
  const int j = idx & 4095;
  float s = 0.f;
  for (int kt = 0; kt < KT; kt++) s += part[((size_t)kt * Bz + b) * HIDz + j];
  out[idx] = s;
}

extern "C" void kernel_launch(void* const* d_in, const int* in_sizes, int n_in,
                              void* d_out, int out_size, void* d_ws, size_t ws_size,
                              hipStream_t stream) {
  const float* hidden = (const float*)d_in[0];
  const int* positions = (const int*)d_in[1];
  const float* kcache = (const float*)d_in[2];
  const float* vcache = (const float*)d_in[3];
  const float* Wqkv = (const float*)d_in[4];
  const float* bqkv = (const float*)d_in[5];
  const float* Wd = (const float*)d_in[6];
  float* out = (float*)d_out;

  const int KT = KTs;
  const int KH = HIDz / KT;

  float* w = (float*)d_ws;
  float* p1 = w;    w += (size_t)KT * Bz * QKVz;
  float* qrot = w;  w += (size_t)Bz * Hz * Dz;
  float* krot = w;  w += (size_t)Bz * Gz * Dz;
  float* vnew = w;  w += (size_t)Bz * Gz * Dz;
  float* mbuf = w;  w += (size_t)Bz * 4 * NCHc * 8;
  float* lbuf = w;  w += (size_t)Bz * 4 * NCHc * 8;
  float* pacc = w;  w += (size_t)Bz * 4 * NCHc * 1024;
  float* ctx = w;

  const size_t smem = (size_t)Bz * (KH + 4) * sizeof(float);

  gemm_partial<<<dim3(QKVz / 128, KT), 256, smem, stream>>>(hidden, Wqkv, p1, HIDz, QKVz, KH);
  qkv_finish<<<dim3(Bz, 9), 256, 0, stream>>>(p1, bqkv, positions, KT, qrot, krot, vnew);
  attn_unit<<<dim3(NCHc, 4, Bz), 256, 0, stream>>>(qrot, kcache, vcache, krot, vnew, positions,
                                                   mbuf, lbuf, pacc);
  attn_combine<<<dim3(Bz * 4), 512, 0, stream>>>(mbuf, lbuf, pacc, positions, ctx);
  gemm_partial<<<dim3(HIDz / 128, KT), 256, smem, stream>>>(ctx, Wd, p1, Hz * Dz, HIDz, KH);
  reduce_out<<<dim3(Bz * HIDz / 256), 256, 0, stream>>>(p1, out, KT);
}

// Round 23
// 137.876 us; speedup vs baseline: 1.3116x; 1.0942x over previous
//
#include <hip/hip_runtime.h>
#include <math.h>

#define Bz 32
#define Sz 4096
#define Hz 32
#define Gz 2
#define Dz 128
#define HIDz 4096
#define QKVz 4608
#define NCHc 32   // combine chunks per (b,y) = blocks; block span <= 128 rows
#define KTs 16    // split-K factor for both GEMMs

static __device__ __forceinline__ void fma4(float4& a, float s, const float4& v) {
  a.x = fmaf(s, v.x, a.x);
  a.y = fmaf(s, v.y, a.y);
  a.z = fmaf(s, v.z, a.z);
  a.w = fmaf(s, v.w, a.w);
}
static __device__ __forceinline__ float dot4(const float4& a, const float4& b, float acc) {
  return fmaf(a.x, b.x, fmaf(a.y, b.y, fmaf(a.z, b.z, fmaf(a.w, b.w, acc))));
}
// direct HBM->LDS, 16 B per lane (wave-uniform LDS base + lane*16 by construction)
static __device__ __forceinline__ void gload16(const float* src, float* ldst) {
  __builtin_amdgcn_global_load_lds(
      (const __attribute__((address_space(1))) void*)src,
      (__attribute__((address_space(3))) void*)ldst, 16, 0, 0);
}

// ---------------- split-K GEMM partial: part[kt][b][j] = sum_{k in chunk} X[b][k]*W[k][j]
// grid (N/128, KTs), block 256. Thread: 4 j-cols x 4 b-rows. 2-deep 4-row W pipeline.
__global__ __launch_bounds__(256) void gemm_partial(
    const float* __restrict__ X, const float* __restrict__ W,
    float* __restrict__ part, int K, int N, int KH) {
  extern __shared__ float hl[];  // [32][KH+4]
  const int stride = KH + 4;
  const int t = threadIdx.x;
  const int k0 = blockIdx.y * KH;
  const int cols4 = KH >> 2;
  const int total4 = Bz * cols4;
  for (int fi = t; fi < total4; fi += 256) {
    const int row = fi / cols4;
    const int c4 = fi - row * cols4;
    const float4 v = *(const float4*)&X[(size_t)row * K + k0 + c4 * 4];
    *(float4*)&hl[row * stride + c4 * 4] = v;
  }
  __syncthreads();
  const int jl = t & 31;
  const int b0 = (t >> 5) * 4;
  const int j = blockIdx.x * 128 + jl * 4;
  float4 acc[4];
  #pragma unroll
  for (int i = 0; i < 4; i++) acc[i] = make_float4(0.f, 0.f, 0.f, 0.f);
  float4 wa[4], wb[4];
#define LDW(buf, kk)                                                      \
  { _Pragma("unroll") for (int r = 0; r < 4; ++r)                         \
      buf[r] = *(const float4*)&W[(size_t)(k0 + (kk) + r) * N + j]; }
#define FMAW(buf, kk)                                                     \
  { _Pragma("unroll") for (int bi = 0; bi < 4; ++bi) {                    \
      const float4 hb = *(const float4*)&hl[(b0 + bi) * stride + (kk)];   \
      fma4(acc[bi], hb.x, buf[0]);                                        \
      fma4(acc[bi], hb.y, buf[1]);                                        \
      fma4(acc[bi], hb.z, buf[2]);                                        \
      fma4(acc[bi], hb.w, buf[3]); } }
  LDW(wa, 0);
  for (int kk = 0; kk < KH; kk += 8) {
    LDW(wb, kk + 4);
    FMAW(wa, kk);
    if (kk + 8 < KH) LDW(wa, kk + 8);
    FMAW(wb, kk + 4);
  }
#undef LDW
#undef FMAW
  #pragma unroll
  for (int bi = 0; bi < 4; bi++) {
    *(float4*)&part[((size_t)blockIdx.y * Bz + b0 + bi) * N + j] = acc[bi];
  }
}

// ---------------- reduce QKV partials + bias, RoPE, emit qrot (pre-scaled), krot, vnew
__global__ __launch_bounds__(256) void qkv_finish(
    const float* __restrict__ part, const float* __restrict__ bias,
    const int* __restrict__ positions, int KT,
    float* __restrict__ qrot, float* __restrict__ krot, float* __restrict__ vnew) {
  const int t = threadIdx.x;
  const int b = blockIdx.x;
  const int head = blockIdx.y * 4 + (t >> 6);
  const int tp = t & 63;
  const int j0 = head * Dz + tp * 2;
  float s0 = bias[j0];
  float s1 = bias[j0 + 1];
  for (int kt = 0; kt < KT; kt++) {
    const float2 p = *(const float2*)&part[((size_t)kt * Bz + b) * QKVz + j0];
    s0 += p.x;
    s1 += p.y;
  }
  float o0 = s0, o1 = s1;
  if (head < Hz + Gz && tp < 32) {
    const float invf = exp2f(-(float)tp * (13.287712379549449f / 32.0f));
    const float a = (float)positions[b] * invf;
    float sn, cs;
    sincosf(a, &sn, &cs);
    o0 = s0 * cs - s1 * sn;
    o1 = s1 * cs + s0 * sn;
  }
  if (head < Hz) {
    const float sc = 0.08838834764831845f;
    float2 o = make_float2(o0 * sc, o1 * sc);
    *(float2*)&qrot[((size_t)b * Hz + head) * Dz + tp * 2] = o;
  } else if (head < Hz + Gz) {
    float2 o = make_float2(o0, o1);
    *(float2*)&krot[((size_t)b * Gz + (head - Hz)) * Dz + tp * 2] = o;
  } else {
    float2 o = make_float2(s0, s1);
    *(float2*)&vnew[((size_t)b * Gz + (head - Hz - Gz)) * Dz + tp * 2] = o;
  }
}

// ---------------- flash block (8 heads): y = blockIdx.y in [0,4): heads y*8..y*8+7,
// KV group g = y>>1. Block bx owns span [bx*(pos+1)/32, (bx+1)*(pos+1)/32) (<=128 rows).
// Wave w owns rows [w*8, w*8+8) of each 32-row tile; K staged via global_load_lds into a
// single wave-private buffer, with STAGE(t+1) issued AFTER tile t's K-reads (buffer dead
// by then) so staging latency hides under softmax+PV -- time-double-buffering at zero LDS
// cost. No barriers in loop. QK lane (hq,rq,cq): 2 heads x 4 rows, Q in registers.
// PV lane = d-pair: V direct from global; P via wave LDS. ~84 VGPR; no spill; 4 blocks/CU.
__global__ __launch_bounds__(256, 2) void attn_unit(
    const float* __restrict__ qrot, const float* __restrict__ kcache,
    const float* __restrict__ vcache, const float* __restrict__ krot,
    const float* __restrict__ vnew, const int* __restrict__ positions,
    float* __restrict__ mbuf, float* __restrict__ lbuf, float* __restrict__ pacc) {
  __shared__ float qs[8 * 132];  // Q staging [h 0..7][c4*4], stride 132
  __shared__ float kbw[4][1024]; // per-wave K buffer (8 rows x 128); aliased as Aw
  __shared__ float plw[4][64];   // per-wave P: [s 0..7][h 0..7]
  __shared__ float scw[4][8];    // per-wave rescale factors
  __shared__ float ml[128];      // m: [w*16+h], l: [64 + w*16+h]
  const int y = blockIdx.y, b = blockIdx.z, bx = blockIdx.x;
  const int g = y >> 1;
  const int pos = positions[b];
  const int lt = pos + 1;
  const int blo = (bx * lt) >> 5;
  const int bhi = ((bx + 1) * lt) >> 5;
  const int nr = bhi - blo;
  const int t = threadIdx.x, w = t >> 6, lane = t & 63;
  const int hq = lane >> 4, rq = (lane >> 3) & 1, cq = lane & 7;
  float* kw = kbw[w];
  float* plv = plw[w];

  // Q tile -> LDS once (pre-scaled). 8 heads x 32 float4 = 256 entries = 1 per thread.
  {
    const int h = t >> 5, c4 = t & 31;
    const float4 q = *(const float4*)&qrot[((size_t)b * Hz + y * 8 + h) * Dz + c4 * 4];
    *(float4*)&qs[h * 132 + c4 * 4] = q;
  }

  const float* krow_new = &krot[((size_t)b * Gz + g) * Dz];
  const float* vrow_new = &vnew[((size_t)b * Gz + g) * Dz];
  const size_t kvb = ((size_t)b * Sz) * (Gz * Dz) + (size_t)g * Dz;

#define STAGE(tile) {                                                              \
    const int sg_ = blo + (tile) * 32 + w * 8 + (lane >> 3);                       \
    const bool fr_ = (sg_ >= bhi) || (sg_ == pos);                                 \
    const float* kp_ = fr_ ? krow_new : &kcache[kvb + (size_t)sg_ * (Gz * Dz)];    \
    gload16(kp_ + (lane & 7) * 4,      &kw[0 * 256 + lane * 4]);                   \
    gload16(kp_ + (lane & 7) * 4 + 32, &kw[1 * 256 + lane * 4]);                   \
    gload16(kp_ + (lane & 7) * 4 + 64, &kw[2 * 256 + lane * 4]);                   \
    gload16(kp_ + (lane & 7) * 4 + 96, &kw[3 * 256 + lane * 4]); }

  float m_run[2], l_run[2];
  float2 A2[8];
  #pragma unroll
  for (int i = 0; i < 2; ++i) { m_run[i] = -1e30f; l_run[i] = 0.f; }
  #pragma unroll
  for (int h = 0; h < 8; ++h) A2[h] = make_float2(0.f, 0.f);

  const int ntw = (nr > w * 8) ? ((nr - w * 8 + 31) >> 5) : 0;  // wave-uniform tiles
  if (ntw > 0) STAGE(0);  // issue before barrier: Q staging + barrier cover part of latency
  __syncthreads();        // qs visible to all waves

  // Q into registers once per block: qr[i][j] = Q[hq*2+i][(cq + 8j)*4 ..]
  float4 qr[2][4];
  #pragma unroll
  for (int i = 0; i < 2; ++i)
    #pragma unroll
    for (int j = 0; j < 4; ++j)
      qr[i][j] = *(const float4*)&qs[(hq * 2 + i) * 132 + (cq + 8 * j) * 4];

  for (int tile = 0; tile < ntw; ++tile) {
    // ---- QK: K from wave LDS buffer, Q from registers
    float lp[2][4];
    #pragma unroll
    for (int i = 0; i < 2; ++i)
      #pragma unroll
      for (int s = 0; s < 4; ++s) lp[i][s] = 0.f;
    #pragma unroll
    for (int j = 0; j < 4; ++j) {
      float4 kf[4];
      #pragma unroll
      for (int s = 0; s < 4; ++s)
        kf[s] = *(const float4*)&kw[j * 256 + ((rq * 4 + s) * 8 + cq) * 4];
      #pragma unroll
      for (int i = 0; i < 2; ++i) {
        #pragma unroll
        for (int s = 0; s < 4; ++s) lp[i][s] = dot4(qr[i][j], kf[s], lp[i][s]);
      }
    }
    // K buffer fully consumed -> stage next tile now; latency hides under softmax+PV.
    if (tile + 1 < ntw) STAGE(tile + 1);
    // reduce over cq lanes
    #pragma unroll
    for (int i = 0; i < 2; ++i)
      #pragma unroll
      for (int s = 0; s < 4; ++s) {
        lp[i][s] += __shfl_xor(lp[i][s], 1);
        lp[i][s] += __shfl_xor(lp[i][s], 2);
        lp[i][s] += __shfl_xor(lp[i][s], 4);
      }
    // mask rows beyond span
    const int rbase = tile * 32 + w * 8 + rq * 4;
    #pragma unroll
    for (int s = 0; s < 4; ++s) {
      if (rbase + s >= nr) {
        lp[0][s] = -1e30f;
        lp[1][s] = -1e30f;
      }
    }
    // ---- online softmax per head
    float sc[2];
    #pragma unroll
    for (int i = 0; i < 2; ++i) {
      float tm = fmaxf(fmaxf(lp[i][0], lp[i][1]), fmaxf(lp[i][2], lp[i][3]));
      tm = fmaxf(tm, __shfl_xor(tm, 8));
      const float mn = fmaxf(m_run[i], tm);
      sc[i] = __expf(m_run[i] - mn);
      m_run[i] = mn;
      float ts = 0.f;
      #pragma unroll
      for (int s = 0; s < 4; ++s) {
        lp[i][s] = __expf(lp[i][s] - mn);
        ts += lp[i][s];
      }
      ts += __shfl_xor(ts, 8);
      l_run[i] = l_run[i] * sc[i] + ts;
    }
    // ---- handoff P and sc (wave-private LDS; same-wave ordering)
    if (cq == 0) {
      if (rq == 0) *(float2*)&scw[w][hq * 2] = make_float2(sc[0], sc[1]);
      #pragma unroll
      for (int s = 0; s < 4; ++s)
        *(float2*)&plv[(rq * 4 + s) * 8 + hq * 2] = make_float2(lp[0][s], lp[1][s]);
    }
    // ---- PV: rescale A2, then accumulate (V direct from global, coalesced)
    {
      const float4 s0 = *(const float4*)&scw[w][0];
      const float4 s1 = *(const float4*)&scw[w][4];
      A2[0].x *= s0.x; A2[0].y *= s0.x;  A2[1].x *= s0.y; A2[1].y *= s0.y;
      A2[2].x *= s0.z; A2[2].y *= s0.z;  A2[3].x *= s0.w; A2[3].y *= s0.w;
      A2[4].x *= s1.x; A2[4].y *= s1.x;  A2[5].x *= s1.y; A2[5].y *= s1.y;
      A2[6].x *= s1.z; A2[6].y *= s1.z;  A2[7].x *= s1.w; A2[7].y *= s1.w;
    }
    #pragma unroll
    for (int s = 0; s < 8; ++s) {
      const int sg = blo + tile * 32 + w * 8 + s;          // wave-uniform
      const float* vp = (sg >= bhi || sg == pos) ? vrow_new
                         : &vcache[kvb + (size_t)sg * (Gz * Dz)];
      const float2 v2 = *(const float2*)&vp[lane * 2];
      const float4 p0 = *(const float4*)&plv[s * 8 + 0];
      const float4 p1 = *(const float4*)&plv[s * 8 + 4];
      A2[0].x = fmaf(p0.x, v2.x, A2[0].x);  A2[0].y = fmaf(p0.x, v2.y, A2[0].y);
      A2[1].x = fmaf(p0.y, v2.x, A2[1].x);  A2[1].y = fmaf(p0.y, v2.y, A2[1].y);
      A2[2].x = fmaf(p0.z, v2.x, A2[2].x);  A2[2].y = fmaf(p0.z, v2.y, A2[2].y);
      A2[3].x = fmaf(p0.w, v2.x, A2[3].x);  A2[3].y = fmaf(p0.w, v2.y, A2[3].y);
      A2[4].x = fmaf(p1.x, v2.x, A2[4].x);  A2[4].y = fmaf(p1.x, v2.y, A2[4].y);
      A2[5].x = fmaf(p1.y, v2.x, A2[5].x);  A2[5].y = fmaf(p1.y, v2.y, A2[5].y);
      A2[6].x = fmaf(p1.z, v2.x, A2[6].x);  A2[6].y = fmaf(p1.z, v2.y, A2[6].y);
      A2[7].x = fmaf(p1.w, v2.x, A2[7].x);  A2[7].y = fmaf(p1.w, v2.y, A2[7].y);
    }
  }

  // ---- in-block combine
  __syncthreads();
  if (cq == 0 && rq == 0) {
    *(float2*)&ml[w * 16 + hq * 2] = make_float2(m_run[0], m_run[1]);
    *(float2*)&ml[64 + w * 16 + hq * 2] = make_float2(l_run[0], l_run[1]);
  }
  __syncthreads();
  float ew[8];
  #pragma unroll
  for (int h = 0; h < 8; ++h) {
    const float ms = fmaxf(fmaxf(ml[h], ml[16 + h]), fmaxf(ml[32 + h], ml[48 + h]));
    ew[h] = __expf(ml[w * 16 + h] - ms);
  }
  float* Aw = &kbw[0][0];  // 8 x 132 (spans kbw[0..1], dead after loop)
  for (int step = 0; step < 4; ++step) {
    if (w == step) {
      #pragma unroll
      for (int h = 0; h < 8; ++h) {
        float2 x;
        if (step == 0) {
          x = make_float2(ew[h] * A2[h].x, ew[h] * A2[h].y);
        } else {
          x = *(const float2*)&Aw[h * 132 + lane * 2];
          x.x = fmaf(ew[h], A2[h].x, x.x);
          x.y = fmaf(ew[h], A2[h].y, x.y);
        }
        *(float2*)&Aw[h * 132 + lane * 2] = x;
      }
    }
    __syncthreads();
  }
  const size_t cb = (size_t)(b * 4 + y) * NCHc + bx;
  {
    const int hh = t >> 5, d4c = t & 31;
    *(float4*)&pacc[cb * 1024 + (size_t)hh * Dz + d4c * 4] =
        *(const float4*)&Aw[hh * 132 + d4c * 4];
  }
  if (t < 8) {
    const int hh = t;
    const float m0 = ml[hh], m1 = ml[16 + hh], m2 = ml[32 + hh], m3 = ml[48 + hh];
    const float msf = fmaxf(fmaxf(m0, m1), fmaxf(m2, m3));
    const float l = __expf(m0 - msf) * ml[64 + hh] + __expf(m1 - msf) * ml[80 + hh] +
                    __expf(m2 - msf) * ml[96 + hh] + __expf(m3 - msf) * ml[112 + hh];
    mbuf[cb * 8 + hh] = msf;
    lbuf[cb * 8 + hh] = l;
  }
#undef STAGE
}

// ---------------- combine chunk partials -> ctx (B, H*D); grid Bz*4, block 512
__global__ __launch_bounds__(512) void attn_combine(
    const float* __restrict__ mbuf, const float* __restrict__ lbuf,
    const float* __restrict__ pacc, const int* __restrict__ positions,
    float* __restrict__ ctx) {
  const int bgH = blockIdx.x;          // b*4 + y
  const int b = bgH >> 2, y = bgH & 3;
  const int t = threadIdx.x;
  const int h = t >> 6, dg = t & 63;   // head 0..7, d-pair 0..63
  float mstar = -1e30f;
  for (int c = 0; c < NCHc; c++) mstar = fmaxf(mstar, mbuf[((size_t)bgH * NCHc + c) * 8 + h]);
  float lsum = 0.f;
  float2 A = make_float2(0.f, 0.f);
  for (int c = 0; c < NCHc; c++) {
    const size_t cb = (size_t)bgH * NCHc + c;
    const float wv = __expf(mbuf[cb * 8 + h] - mstar);
    lsum += wv * lbuf[cb * 8 + h];
    const float2 p = *(const float2*)&pacc[cb * 1024 + (size_t)h * Dz + dg * 2];
    A.x = fmaf(wv, p.x, A.x);
    A.y = fmaf(wv, p.y, A.y);
  }
  const float inv = 1.0f / lsum;
  float2 o = make_float2(A.x * inv, A.y * inv);
  *(float2*)&ctx[(size_t)b * (Hz * Dz) + (y * 8 + h) * Dz + dg * 2] = o;
}

// ---------------- reduce dense partials -> out
__global__ __launch_bounds__(256) void reduce_out(
    const float* __restrict__ part, float* __restrict__ out, int KT) {
  const int idx = blockIdx.x * 256 + threadIdx.x;
  const int b = idx >> 12;
  const int j = idx & 4095;
  float s = 0.f;
  for (int kt = 0; kt < KT; kt++) s += part[((size_t)kt * Bz + b) * HIDz + j];
  out[idx] = s;
}

extern "C" void kernel_launch(void* const* d_in, const int* in_sizes, int n_in,
                              void* d_out, int out_size, void* d_ws, size_t ws_size,
                              hipStream_t stream) {
  const float* hidden = (const float*)d_in[0];
  const int* positions = (const int*)d_in[1];
  const float* kcache = (const float*)d_in[2];
  const float* vcache = (const float*)d_in[3];
  const float* Wqkv = (const float*)d_in[4];
  const float* bqkv = (const float*)d_in[5];
  const float* Wd = (const float*)d_in[6];
  float* out = (float*)d_out;

  const int KT = KTs;
  const int KH = HIDz / KT;

  float* w = (float*)d_ws;
  float* p1 = w;    w += (size_t)KT * Bz * QKVz;
  float* qrot = w;  w += (size_t)Bz * Hz * Dz;
  float* krot = w;  w += (size_t)Bz * Gz * Dz;
  float* vnew = w;  w += (size_t)Bz * Gz * Dz;
  float* mbuf = w;  w += (size_t)Bz * 4 * NCHc * 8;
  float* lbuf = w;  w += (size_t)Bz * 4 * NCHc * 8;
  float* pacc = w;  w += (size_t)Bz * 4 * NCHc * 1024;
  float* ctx = w;

  const size_t smem = (size_t)Bz * (KH + 4) * sizeof(float);

  gemm_partial<<<dim3(QKVz / 128, KT), 256, smem, stream>>>(hidden, Wqkv, p1, HIDz, QKVz, KH);
  qkv_finish<<<dim3(Bz, 9), 256, 0, stream>>>(p1, bqkv, positions, KT, qrot, krot, vnew);
  attn_unit<<<dim3(NCHc, 4, Bz), 256, 0, stream>>>(qrot, kcache, vcache, krot, vnew, positions,
                                                   mbuf, lbuf, pacc);
  attn_combine<<<dim3(Bz * 4), 512, 0, stream>>>(mbuf, lbuf, pacc, positions, ctx);
  gemm_partial<<<dim3(HIDz / 128, KT), 256, smem, stream>>>(ctx, Wd, p1, Hz * Dz, HIDz, KH);
  reduce_out<<<dim3(Bz * HIDz / 256), 256, 0, stream>>>(p1, out, KT);
}